// Round 1
// baseline (122.667 us; speedup 1.0000x reference)
//
#include <hip/hip_runtime.h>

constexpr int   P     = 512;
constexpr int   W     = 256;
constexpr int   H     = 256;
constexpr float FXc   = 256.0f;           // W / (2*tanfovx)
constexpr float FYc   = 256.0f;
constexpr float NEARc = 0.2f;
constexpr float BLUR  = 0.3f;
constexpr float LIMX  = 0.65f;            // 1.3 * tanfovx
constexpr float LIMY  = 0.65f;

// d_out layout (all read back as float32 by the harness):
constexpr int COLOR_OFF = 0;              // 3*H*W = 196608
constexpr int RADII_OFF = 196608;         // 512
constexpr int DEPTH_OFF = 197120;         // 65536
constexpr int OPAC_OFF  = 262656;         // 65536
constexpr int NT_OFF    = 328192;         // 512

// ws layout: 12 SoA arrays of length P (sorted order)
// 0:px 1:py 2:ca 3:cb 4:cc 5:op 6:r 7:g 8:b 9:dep 10:valid 11:orig-idx(int)

__global__ __launch_bounds__(512) void prep_sort_kernel(
    const float* __restrict__ means3D, const float* __restrict__ scales,
    const float* __restrict__ rots,    const float* __restrict__ opac,
    const float* __restrict__ cols,    const float* __restrict__ vm,
    const float* __restrict__ pm,      float* __restrict__ out,
    float* __restrict__ ws)
{
    const int i = threadIdx.x;
    __shared__ float s_depth[P];

    const float mx = means3D[i*3+0], my = means3D[i*3+1], mz = means3D[i*3+2];

    // p_view = Rw @ m + t    (vm row-major 4x4)
    const float pv0 = vm[0]*mx + vm[1]*my + vm[2]*mz  + vm[3];
    const float pv1 = vm[4]*mx + vm[5]*my + vm[6]*mz  + vm[7];
    const float pv2 = vm[8]*mx + vm[9]*my + vm[10]*mz + vm[11];
    const float depth = pv2;

    // p_hom = [m,1] @ proj^T
    const float ph0 = pm[0]*mx  + pm[1]*my  + pm[2]*mz  + pm[3];
    const float ph1 = pm[4]*mx  + pm[5]*my  + pm[6]*mz  + pm[7];
    const float ph3 = pm[12]*mx + pm[13]*my + pm[14]*mz + pm[15];
    const float pwn = 1.0f / (ph3 + 1e-7f);
    const float pp0 = ph0 * pwn, pp1 = ph1 * pwn;

    // quaternion -> rotation
    float q0 = rots[i*4+0], q1 = rots[i*4+1], q2 = rots[i*4+2], q3 = rots[i*4+3];
    const float qinv = 1.0f / sqrtf(q0*q0 + q1*q1 + q2*q2 + q3*q3);
    q0 *= qinv; q1 *= qinv; q2 *= qinv; q3 *= qinv;
    const float r = q0, x = q1, y = q2, z = q3;
    const float R00 = 1.f - 2.f*(y*y + z*z), R01 = 2.f*(x*y - r*z), R02 = 2.f*(x*z + r*y);
    const float R10 = 2.f*(x*y + r*z), R11 = 1.f - 2.f*(x*x + z*z), R12 = 2.f*(y*z - r*x);
    const float R20 = 2.f*(x*z - r*y), R21 = 2.f*(y*z + r*x), R22 = 1.f - 2.f*(x*x + y*y);

    const float s0 = scales[i*3+0], s1 = scales[i*3+1], s2 = scales[i*3+2];
    // M = R * diag(s); cov3d = M M^T (symmetric)
    const float M00 = R00*s0, M01 = R01*s1, M02 = R02*s2;
    const float M10 = R10*s0, M11 = R11*s1, M12 = R12*s2;
    const float M20 = R20*s0, M21 = R21*s1, M22 = R22*s2;
    const float c00 = M00*M00 + M01*M01 + M02*M02;
    const float c01 = M00*M10 + M01*M11 + M02*M12;
    const float c02 = M00*M20 + M01*M21 + M02*M22;
    const float c11 = M10*M10 + M11*M11 + M12*M12;
    const float c12 = M10*M20 + M11*M21 + M12*M22;
    const float c22 = M20*M20 + M21*M21 + M22*M22;

    const float tz  = (fabsf(depth) < 1e-6f) ? 1e-6f : depth;
    const float txc = fminf(fmaxf(pv0 / tz, -LIMX), LIMX) * tz;
    const float tyc = fminf(fmaxf(pv1 / tz, -LIMY), LIMY) * tz;

    const float J00 = FXc / tz, J02 = -FXc * txc / (tz*tz);
    const float J11 = FYc / tz, J12 = -FYc * tyc / (tz*tz);

    // T2 = J @ Rw
    const float T00 = J00*vm[0] + J02*vm[8];
    const float T01 = J00*vm[1] + J02*vm[9];
    const float T02 = J00*vm[2] + J02*vm[10];
    const float T10 = J11*vm[4] + J12*vm[8];
    const float T11 = J11*vm[5] + J12*vm[9];
    const float T12 = J11*vm[6] + J12*vm[10];

    // V = T2 @ cov3d ; cov2d = V @ T2^T
    const float V00 = T00*c00 + T01*c01 + T02*c02;
    const float V01 = T00*c01 + T01*c11 + T02*c12;
    const float V02 = T00*c02 + T01*c12 + T02*c22;
    const float V10 = T10*c00 + T11*c01 + T12*c02;
    const float V11 = T10*c01 + T11*c11 + T12*c12;
    const float V12 = T10*c02 + T11*c12 + T12*c22;

    const float a = V00*T00 + V01*T01 + V02*T02 + BLUR;
    const float b = V00*T10 + V01*T11 + V02*T12;
    const float c = V10*T10 + V11*T11 + V12*T12 + BLUR;
    const float det = a*c - b*b;

    const bool  valid = (depth > NEARc) && (det > 0.0f);
    const float det_s = valid ? det : 1.0f;
    const float ca =  c / det_s;
    const float cb = -b / det_s;
    const float cc =  a / det_s;

    const float mid = 0.5f * (a + c);
    const float lam = mid + sqrtf(fmaxf(mid*mid - det, 0.1f));
    const int   radii = valid ? (int)ceilf(3.0f * sqrtf(lam)) : 0;

    const float px = ((pp0 + 1.0f) * (float)W - 1.0f) * 0.5f;
    const float py = ((pp1 + 1.0f) * (float)H - 1.0f) * 0.5f;

    out[RADII_OFF + i] = (float)radii;
    out[NT_OFF + i]    = 0.0f;             // zero before blend's atomics

    // stable rank sort by depth
    s_depth[i] = depth;
    __syncthreads();
    int rank = 0;
    #pragma unroll 8
    for (int j = 0; j < P; ++j) {
        const float dj = s_depth[j];
        rank += (dj < depth) || (dj == depth && j < i);
    }

    ws[0*P + rank]  = px;
    ws[1*P + rank]  = py;
    ws[2*P + rank]  = ca;
    ws[3*P + rank]  = cb;
    ws[4*P + rank]  = cc;
    ws[5*P + rank]  = opac[i];
    ws[6*P + rank]  = cols[i*3+0];
    ws[7*P + rank]  = cols[i*3+1];
    ws[8*P + rank]  = cols[i*3+2];
    ws[9*P + rank]  = depth;
    ws[10*P + rank] = valid ? 1.0f : 0.0f;
    ((int*)ws)[11*P + rank] = i;
}

__global__ __launch_bounds__(256) void blend_kernel(
    const float* __restrict__ ws, const float* __restrict__ bg,
    float* __restrict__ out)
{
    __shared__ float g[12 * P];            // 24 KiB
    for (int t = threadIdx.x; t < 12 * P; t += 256) g[t] = ws[t];
    __syncthreads();

    const int   pix = blockIdx.x * 256 + threadIdx.x;
    const float fx  = (float)(pix & (W - 1));
    const float fy  = (float)(pix >> 8);

    float T = 1.0f, accr = 0.0f, accg = 0.0f, accb = 0.0f, accd = 0.0f;
    const bool lane0 = ((threadIdx.x & 63) == 0);
    float* __restrict__ nt = out + NT_OFF;
    const int* __restrict__ gi = (const int*)g;

    for (int i = 0; i < P; ++i) {
        const float dx = g[0*P + i] - fx;
        const float dy = g[1*P + i] - fy;
        const float ca = g[2*P + i], cb = g[3*P + i], cc = g[4*P + i];
        const float power = -0.5f * (ca*dx*dx + cc*dy*dy) - cb*dx*dy;
        const float alpha = fminf(0.99f, g[5*P + i] * expf(power));
        const bool keep = (power <= 0.0f) && (alpha >= (1.0f/255.0f))
                          && (g[10*P + i] != 0.0f);

        const unsigned long long m = __ballot(keep);
        if (lane0 && m)
            atomicAdd(&nt[gi[11*P + i]], (float)__popcll(m));

        if (keep) {
            const float w = alpha * T;
            accr += w * g[6*P + i];
            accg += w * g[7*P + i];
            accb += w * g[8*P + i];
            accd += w * g[9*P + i];
            T *= (1.0f - alpha);
        }
    }

    const float b0 = bg[0], b1 = bg[1], b2 = bg[2];
    out[COLOR_OFF + 0*65536 + pix] = accr + T * b0;
    out[COLOR_OFF + 1*65536 + pix] = accg + T * b1;
    out[COLOR_OFF + 2*65536 + pix] = accb + T * b2;
    out[DEPTH_OFF + pix]           = accd;
    out[OPAC_OFF  + pix]           = 1.0f - T;
}

extern "C" void kernel_launch(void* const* d_in, const int* in_sizes, int n_in,
                              void* d_out, int out_size, void* d_ws, size_t ws_size,
                              hipStream_t stream) {
    const float* means3D = (const float*)d_in[0];
    const float* scales  = (const float*)d_in[1];
    const float* rots    = (const float*)d_in[2];
    const float* opac    = (const float*)d_in[3];
    const float* cols    = (const float*)d_in[4];
    const float* vm      = (const float*)d_in[5];
    const float* pm      = (const float*)d_in[6];
    // d_in[7] = campos (unused by reference math)
    const float* bg      = (const float*)d_in[8];
    float* out = (float*)d_out;
    float* ws  = (float*)d_ws;

    prep_sort_kernel<<<1, 512, 0, stream>>>(means3D, scales, rots, opac, cols,
                                            vm, pm, out, ws);
    blend_kernel<<<(H * W) / 256, 256, 0, stream>>>(ws, bg, out);
}

// Round 2
// 43.988 us; speedup vs baseline: 2.7887x; 2.7887x over previous
//
#include <hip/hip_runtime.h>

constexpr int   P     = 512;
constexpr int   W     = 256;
constexpr int   H     = 256;
constexpr float FXc   = 256.0f;
constexpr float FYc   = 256.0f;
constexpr float NEARc = 0.2f;
constexpr float BLUR  = 0.3f;
constexpr float LIMX  = 0.65f;
constexpr float LIMY  = 0.65f;

// d_out layout (floats)
constexpr int COLOR_OFF = 0;
constexpr int RADII_OFF = 196608;
constexpr int DEPTH_OFF = 197120;
constexpr int OPAC_OFF  = 262656;
constexpr int NT_OFF    = 328192;

// d_ws layout (4-byte element offsets)
// GPACK: 512 gaussians x 12 floats, sorted order:
//   [0]=py [1]=rowrad2 [2]=px [3]=ca [4]=cb [5]=cc [6]=op [7]=dep [8..10]=rgb [11]=pad
constexpr int GPACK_OFF = 0;                 // 6144 floats
constexpr int IDX_OFF   = 6144;              // 512 ints (sorted rank -> orig index)
constexpr int NTP_OFF   = 6656;              // H*P = 131072 ints: ntp[row*512 + rank]
constexpr int PART_OFF  = NTP_OFF + H * P;   // 5*S*65536 floats: [(c*S+s)*65536 + pix]

__global__ __launch_bounds__(512) void prep_sort_kernel(
    const float* __restrict__ means3D, const float* __restrict__ scales,
    const float* __restrict__ rots,    const float* __restrict__ opacs,
    const float* __restrict__ cols,    const float* __restrict__ vm,
    const float* __restrict__ pm,      float* __restrict__ out,
    float* __restrict__ ws)
{
    const int i = threadIdx.x;
    __shared__ float s_depth[P];

    const float mx = means3D[i*3+0], my = means3D[i*3+1], mz = means3D[i*3+2];

    const float pv0 = vm[0]*mx + vm[1]*my + vm[2]*mz  + vm[3];
    const float pv1 = vm[4]*mx + vm[5]*my + vm[6]*mz  + vm[7];
    const float pv2 = vm[8]*mx + vm[9]*my + vm[10]*mz + vm[11];
    const float depth = pv2;

    const float ph0 = pm[0]*mx  + pm[1]*my  + pm[2]*mz  + pm[3];
    const float ph1 = pm[4]*mx  + pm[5]*my  + pm[6]*mz  + pm[7];
    const float ph3 = pm[12]*mx + pm[13]*my + pm[14]*mz + pm[15];
    const float pwn = 1.0f / (ph3 + 1e-7f);
    const float pp0 = ph0 * pwn, pp1 = ph1 * pwn;

    float q0 = rots[i*4+0], q1 = rots[i*4+1], q2 = rots[i*4+2], q3 = rots[i*4+3];
    const float qinv = 1.0f / sqrtf(q0*q0 + q1*q1 + q2*q2 + q3*q3);
    q0 *= qinv; q1 *= qinv; q2 *= qinv; q3 *= qinv;
    const float r = q0, x = q1, y = q2, z = q3;
    const float R00 = 1.f - 2.f*(y*y + z*z), R01 = 2.f*(x*y - r*z), R02 = 2.f*(x*z + r*y);
    const float R10 = 2.f*(x*y + r*z), R11 = 1.f - 2.f*(x*x + z*z), R12 = 2.f*(y*z - r*x);
    const float R20 = 2.f*(x*z - r*y), R21 = 2.f*(y*z + r*x), R22 = 1.f - 2.f*(x*x + y*y);

    const float s0 = scales[i*3+0], s1 = scales[i*3+1], s2 = scales[i*3+2];
    const float M00 = R00*s0, M01 = R01*s1, M02 = R02*s2;
    const float M10 = R10*s0, M11 = R11*s1, M12 = R12*s2;
    const float M20 = R20*s0, M21 = R21*s1, M22 = R22*s2;
    const float c00 = M00*M00 + M01*M01 + M02*M02;
    const float c01 = M00*M10 + M01*M11 + M02*M12;
    const float c02 = M00*M20 + M01*M21 + M02*M22;
    const float c11 = M10*M10 + M11*M11 + M12*M12;
    const float c12 = M10*M20 + M11*M21 + M12*M22;
    const float c22 = M20*M20 + M21*M21 + M22*M22;

    const float tz  = (fabsf(depth) < 1e-6f) ? 1e-6f : depth;
    const float txc = fminf(fmaxf(pv0 / tz, -LIMX), LIMX) * tz;
    const float tyc = fminf(fmaxf(pv1 / tz, -LIMY), LIMY) * tz;

    const float J00 = FXc / tz, J02 = -FXc * txc / (tz*tz);
    const float J11 = FYc / tz, J12 = -FYc * tyc / (tz*tz);

    const float T00 = J00*vm[0] + J02*vm[8];
    const float T01 = J00*vm[1] + J02*vm[9];
    const float T02 = J00*vm[2] + J02*vm[10];
    const float T10 = J11*vm[4] + J12*vm[8];
    const float T11 = J11*vm[5] + J12*vm[9];
    const float T12 = J11*vm[6] + J12*vm[10];

    const float V00 = T00*c00 + T01*c01 + T02*c02;
    const float V01 = T00*c01 + T01*c11 + T02*c12;
    const float V02 = T00*c02 + T01*c12 + T02*c22;
    const float V10 = T10*c00 + T11*c01 + T12*c02;
    const float V11 = T10*c01 + T11*c11 + T12*c12;
    const float V12 = T10*c02 + T11*c12 + T12*c22;

    const float a = V00*T00 + V01*T01 + V02*T02 + BLUR;
    const float b = V00*T10 + V01*T11 + V02*T12;
    const float c = V10*T10 + V11*T11 + V12*T12 + BLUR;
    const float det = a*c - b*b;

    const bool  valid = (depth > NEARc) && (det > 0.0f);
    const float det_s = valid ? det : 1.0f;
    const float ca =  c / det_s;
    const float cb = -b / det_s;
    const float cc =  a / det_s;

    const float mid = 0.5f * (a + c);
    const float lam = mid + sqrtf(fmaxf(mid*mid - det, 0.1f));
    const int   radii = valid ? (int)ceilf(3.0f * sqrtf(lam)) : 0;

    const float px = ((pp0 + 1.0f) * (float)W - 1.0f) * 0.5f;
    const float py = ((pp1 + 1.0f) * (float)H - 1.0f) * 0.5f;

    const float op = opacs[i];
    // Row-cull radius^2: keep possible in a row iff dy^2 <= 2*c*ln(255*op).
    // (max over dx of power is -0.5*dy^2/c;  c = cov2d[1,1]+blur = 1/(cc - cb^2/ca))
    const float rowrad2 = valid ? (2.0f * c * logf(255.0f * op)) : -1.0f;

    out[RADII_OFF + i] = (float)radii;
    out[NT_OFF + i]    = 0.0f;   // nt_reduce atomically accumulates on top

    s_depth[i] = depth;
    __syncthreads();
    int rank = 0;
    #pragma unroll 8
    for (int j = 0; j < P; ++j) {
        const float dj = s_depth[j];
        rank += (dj < depth) || (dj == depth && j < i);
    }

    float* gp = ws + GPACK_OFF + rank * 12;
    gp[0]  = py;     gp[1]  = rowrad2; gp[2]  = px;  gp[3]  = ca;
    gp[4]  = cb;     gp[5]  = cc;      gp[6]  = op;  gp[7]  = depth;
    gp[8]  = cols[i*3+0]; gp[9] = cols[i*3+1]; gp[10] = cols[i*3+2]; gp[11] = 0.0f;
    ((int*)ws)[IDX_OFF + rank] = i;
}

template <int S>
__global__ __launch_bounds__(256) void blend_seg_kernel(float* ws)
{
    constexpr int PSEG = P / S;
    __shared__ float sg[PSEG * 12];
    __shared__ int   snt[PSEG];

    const int seg = blockIdx.y;
    const int row = blockIdx.x;

    const float* src = ws + GPACK_OFF + seg * PSEG * 12;
    for (int t = threadIdx.x; t < PSEG * 12; t += 256) sg[t] = src[t];
    for (int t = threadIdx.x; t < PSEG;      t += 256) snt[t] = 0;
    __syncthreads();

    const float fx = (float)threadIdx.x;
    const float fy = (float)row;
    const float4* g4 = (const float4*)sg;
    const bool lane0 = ((threadIdx.x & 63) == 0);

    float T = 1.0f, ar = 0.f, ag = 0.f, ab = 0.f, ad = 0.f;

    for (int i = 0; i < PSEG; ++i) {
        const float4 h = g4[i*3+0];           // py, rowrad2, px, ca
        const float dy = h.x - fy;
        if (dy*dy > h.y) continue;            // whole-row cull (uniform branch)
        const float4 m  = g4[i*3+1];          // cb, cc, op, dep
        const float4 cl = g4[i*3+2];          // r, g, b, pad
        const float dx = h.z - fx;
        const float power = -0.5f*(h.w*dx*dx + m.y*dy*dy) - m.x*dx*dy;
        const float alpha = fminf(0.99f, m.z * __expf(power));
        const bool keep = (power <= 0.0f) && (alpha >= (1.0f/255.0f));

        const unsigned long long msk = __ballot(keep);
        if (lane0 && msk) atomicAdd(&snt[i], __popcll(msk));

        if (keep) {
            const float w = alpha * T;
            ar += w * cl.x; ag += w * cl.y; ab += w * cl.z; ad += w * m.w;
            T *= (1.0f - alpha);
        }
    }
    __syncthreads();

    int* ntp = ((int*)ws) + NTP_OFF;
    for (int t = threadIdx.x; t < PSEG; t += 256)
        ntp[row * P + seg * PSEG + t] = snt[t];

    const int pix = row * W + threadIdx.x;
    float* part = ws + PART_OFF;
    part[(0*S + seg)*65536 + pix] = ar;
    part[(1*S + seg)*65536 + pix] = ag;
    part[(2*S + seg)*65536 + pix] = ab;
    part[(3*S + seg)*65536 + pix] = ad;
    part[(4*S + seg)*65536 + pix] = T;
}

template <int S>
__global__ __launch_bounds__(256) void combine_kernel(
    const float* __restrict__ ws, const float* __restrict__ bg,
    float* __restrict__ out)
{
    const int pix = blockIdx.x * 256 + threadIdx.x;
    const float* part = ws + PART_OFF;
    float T = 1.0f, r = 0.f, g = 0.f, b = 0.f, d = 0.f;
    #pragma unroll
    for (int s = 0; s < S; ++s) {
        const float pr = part[(0*S + s)*65536 + pix];
        const float pg = part[(1*S + s)*65536 + pix];
        const float pb = part[(2*S + s)*65536 + pix];
        const float pd = part[(3*S + s)*65536 + pix];
        const float pT = part[(4*S + s)*65536 + pix];
        r += T * pr; g += T * pg; b += T * pb; d += T * pd;
        T *= pT;
    }
    out[COLOR_OFF + 0*65536 + pix] = r + T * bg[0];
    out[COLOR_OFF + 1*65536 + pix] = g + T * bg[1];
    out[COLOR_OFF + 2*65536 + pix] = b + T * bg[2];
    out[DEPTH_OFF + pix]           = d;
    out[OPAC_OFF  + pix]           = 1.0f - T;
}

// 16 blocks x 512 threads; block handles 16 rows of the ntp matrix.
__global__ __launch_bounds__(512) void nt_reduce_kernel(
    const float* __restrict__ ws, float* __restrict__ out)
{
    const int g  = threadIdx.x;
    const int r0 = blockIdx.x * 16;
    const int* ntp = ((const int*)ws) + NTP_OFF;
    int sum = 0;
    #pragma unroll 4
    for (int r = 0; r < 16; ++r) sum += ntp[(r0 + r) * P + g];
    if (sum) {
        const int orig = ((const int*)ws)[IDX_OFF + g];
        atomicAdd(&out[NT_OFF + orig], (float)sum);
    }
}

// Fallback: single-pass direct blend (used only if ws is too small for partials).
__global__ __launch_bounds__(256) void blend_direct_kernel(
    float* ws, const float* __restrict__ bg, float* __restrict__ out)
{
    __shared__ float sg[P * 12];
    __shared__ int   snt[P];
    for (int t = threadIdx.x; t < P * 12; t += 256) sg[t] = ws[GPACK_OFF + t];
    for (int t = threadIdx.x; t < P;      t += 256) snt[t] = 0;
    __syncthreads();

    const int row = blockIdx.x;
    const float fx = (float)threadIdx.x;
    const float fy = (float)row;
    const float4* g4 = (const float4*)sg;
    const bool lane0 = ((threadIdx.x & 63) == 0);

    float T = 1.0f, ar = 0.f, ag = 0.f, ab = 0.f, ad = 0.f;
    for (int i = 0; i < P; ++i) {
        const float4 h = g4[i*3+0];
        const float dy = h.x - fy;
        if (dy*dy > h.y) continue;
        const float4 m  = g4[i*3+1];
        const float4 cl = g4[i*3+2];
        const float dx = h.z - fx;
        const float power = -0.5f*(h.w*dx*dx + m.y*dy*dy) - m.x*dx*dy;
        const float alpha = fminf(0.99f, m.z * __expf(power));
        const bool keep = (power <= 0.0f) && (alpha >= (1.0f/255.0f));
        const unsigned long long msk = __ballot(keep);
        if (lane0 && msk) atomicAdd(&snt[i], __popcll(msk));
        if (keep) {
            const float w = alpha * T;
            ar += w * cl.x; ag += w * cl.y; ab += w * cl.z; ad += w * m.w;
            T *= (1.0f - alpha);
        }
    }
    __syncthreads();
    const int* idx = ((const int*)ws) + IDX_OFF;
    for (int t = threadIdx.x; t < P; t += 256)
        if (snt[t]) atomicAdd(&out[NT_OFF + idx[t]], (float)snt[t]);

    const int pix = row * W + threadIdx.x;
    out[COLOR_OFF + 0*65536 + pix] = ar + T * bg[0];
    out[COLOR_OFF + 1*65536 + pix] = ag + T * bg[1];
    out[COLOR_OFF + 2*65536 + pix] = ab + T * bg[2];
    out[DEPTH_OFF + pix]           = ad;
    out[OPAC_OFF  + pix]           = 1.0f - T;
}

extern "C" void kernel_launch(void* const* d_in, const int* in_sizes, int n_in,
                              void* d_out, int out_size, void* d_ws, size_t ws_size,
                              hipStream_t stream) {
    const float* means3D = (const float*)d_in[0];
    const float* scales  = (const float*)d_in[1];
    const float* rots    = (const float*)d_in[2];
    const float* opacs   = (const float*)d_in[3];
    const float* cols    = (const float*)d_in[4];
    const float* vm      = (const float*)d_in[5];
    const float* pm      = (const float*)d_in[6];
    const float* bg      = (const float*)d_in[8];
    float* out = (float*)d_out;
    float* ws  = (float*)d_ws;

    prep_sort_kernel<<<1, 512, 0, stream>>>(means3D, scales, rots, opacs, cols,
                                            vm, pm, out, ws);

    constexpr int S = 4;
    const size_t need = (size_t)(PART_OFF + 5 * S * 65536) * 4;
    if (ws_size >= need) {
        blend_seg_kernel<S><<<dim3(H, S), 256, 0, stream>>>(ws);
        combine_kernel<S><<<(H * W) / 256, 256, 0, stream>>>(ws, bg, out);
        nt_reduce_kernel<<<16, 512, 0, stream>>>(ws, out);
    } else {
        blend_direct_kernel<<<H, 256, 0, stream>>>(ws, bg, out);
    }
}

// Round 3
// 37.965 us; speedup vs baseline: 3.2310x; 1.1586x over previous
//
#include <hip/hip_runtime.h>

constexpr int   P     = 512;
constexpr int   W     = 256;
constexpr int   H     = 256;
constexpr float FXc   = 256.0f;
constexpr float FYc   = 256.0f;
constexpr float NEARc = 0.2f;
constexpr float BLUR  = 0.3f;
constexpr float LIMX  = 0.65f;
constexpr float LIMY  = 0.65f;

// d_out layout (floats)
constexpr int COLOR_OFF = 0;
constexpr int RADII_OFF = 196608;
constexpr int DEPTH_OFF = 197120;
constexpr int OPAC_OFF  = 262656;
constexpr int NT_OFF    = 328192;

// d_ws layout (4-byte element offsets)
// GPACK: 512 x 12 floats (sorted):
//   [0]=py [1]=rowrad2 [2]=px [3]=ca | [4]=cb [5]=cc [6]=op [7]=dep | [8..10]=rgb [11]=pad
constexpr int GPACK_OFF = 0;          // 6144 floats
constexpr int IDX_OFF   = 6144;       // 512 ints (rank -> orig index)
constexpr int HDR_OFF   = 6656;       // 512 float2 = 1024 floats (py, rowrad2)
constexpr int PART_OFF  = 7680;       // 5*S*65536 floats
constexpr int S         = 4;          // depth segments

__global__ __launch_bounds__(512) void prep_sort_kernel(
    const float* __restrict__ means3D, const float* __restrict__ scales,
    const float* __restrict__ rots,    const float* __restrict__ opacs,
    const float* __restrict__ cols,    const float* __restrict__ vm,
    const float* __restrict__ pm,      float* __restrict__ out,
    float* __restrict__ ws)
{
    const int i = threadIdx.x;
    __shared__ float s_depth[P];

    const float mx = means3D[i*3+0], my = means3D[i*3+1], mz = means3D[i*3+2];

    const float pv0 = vm[0]*mx + vm[1]*my + vm[2]*mz  + vm[3];
    const float pv1 = vm[4]*mx + vm[5]*my + vm[6]*mz  + vm[7];
    const float pv2 = vm[8]*mx + vm[9]*my + vm[10]*mz + vm[11];
    const float depth = pv2;

    const float ph0 = pm[0]*mx  + pm[1]*my  + pm[2]*mz  + pm[3];
    const float ph1 = pm[4]*mx  + pm[5]*my  + pm[6]*mz  + pm[7];
    const float ph3 = pm[12]*mx + pm[13]*my + pm[14]*mz + pm[15];
    const float pwn = 1.0f / (ph3 + 1e-7f);
    const float pp0 = ph0 * pwn, pp1 = ph1 * pwn;

    float q0 = rots[i*4+0], q1 = rots[i*4+1], q2 = rots[i*4+2], q3 = rots[i*4+3];
    const float qinv = 1.0f / sqrtf(q0*q0 + q1*q1 + q2*q2 + q3*q3);
    q0 *= qinv; q1 *= qinv; q2 *= qinv; q3 *= qinv;
    const float r = q0, x = q1, y = q2, z = q3;
    const float R00 = 1.f - 2.f*(y*y + z*z), R01 = 2.f*(x*y - r*z), R02 = 2.f*(x*z + r*y);
    const float R10 = 2.f*(x*y + r*z), R11 = 1.f - 2.f*(x*x + z*z), R12 = 2.f*(y*z - r*x);
    const float R20 = 2.f*(x*z - r*y), R21 = 2.f*(y*z + r*x), R22 = 1.f - 2.f*(x*x + y*y);

    const float s0 = scales[i*3+0], s1 = scales[i*3+1], s2 = scales[i*3+2];
    const float M00 = R00*s0, M01 = R01*s1, M02 = R02*s2;
    const float M10 = R10*s0, M11 = R11*s1, M12 = R12*s2;
    const float M20 = R20*s0, M21 = R21*s1, M22 = R22*s2;
    const float c00 = M00*M00 + M01*M01 + M02*M02;
    const float c01 = M00*M10 + M01*M11 + M02*M12;
    const float c02 = M00*M20 + M01*M21 + M02*M22;
    const float c11 = M10*M10 + M11*M11 + M12*M12;
    const float c12 = M10*M20 + M11*M21 + M12*M22;
    const float c22 = M20*M20 + M21*M21 + M22*M22;

    const float tz  = (fabsf(depth) < 1e-6f) ? 1e-6f : depth;
    const float txc = fminf(fmaxf(pv0 / tz, -LIMX), LIMX) * tz;
    const float tyc = fminf(fmaxf(pv1 / tz, -LIMY), LIMY) * tz;

    const float J00 = FXc / tz, J02 = -FXc * txc / (tz*tz);
    const float J11 = FYc / tz, J12 = -FYc * tyc / (tz*tz);

    const float T00 = J00*vm[0] + J02*vm[8];
    const float T01 = J00*vm[1] + J02*vm[9];
    const float T02 = J00*vm[2] + J02*vm[10];
    const float T10 = J11*vm[4] + J12*vm[8];
    const float T11 = J11*vm[5] + J12*vm[9];
    const float T12 = J11*vm[6] + J12*vm[10];

    const float V00 = T00*c00 + T01*c01 + T02*c02;
    const float V01 = T00*c01 + T01*c11 + T02*c12;
    const float V02 = T00*c02 + T01*c12 + T02*c22;
    const float V10 = T10*c00 + T11*c01 + T12*c02;
    const float V11 = T10*c01 + T11*c11 + T12*c12;
    const float V12 = T10*c02 + T11*c12 + T12*c22;

    const float a = V00*T00 + V01*T01 + V02*T02 + BLUR;
    const float b = V00*T10 + V01*T11 + V02*T12;
    const float c = V10*T10 + V11*T11 + V12*T12 + BLUR;
    const float det = a*c - b*b;

    const bool  valid = (depth > NEARc) && (det > 0.0f);
    const float det_s = valid ? det : 1.0f;
    const float ca =  c / det_s;
    const float cb = -b / det_s;
    const float cc =  a / det_s;

    const float mid = 0.5f * (a + c);
    const float lam = mid + sqrtf(fmaxf(mid*mid - det, 0.1f));
    const int   radii = valid ? (int)ceilf(3.0f * sqrtf(lam)) : 0;

    const float px = ((pp0 + 1.0f) * (float)W - 1.0f) * 0.5f;
    const float py = ((pp1 + 1.0f) * (float)H - 1.0f) * 0.5f;

    const float op = opacs[i];
    // Row-cull bound: keep possible in row iff dy^2 <= 2*c*ln(255*op).
    // Tiny margin so fp rounding never culls a pixel the reference keeps.
    const float rowrad2 = valid ? (2.0f * c * logf(255.0f * op)) * 1.0001f + 1e-4f
                                : -1.0f;

    out[RADII_OFF + i] = (float)radii;
    out[NT_OFF + i]    = 0.0f;      // blend atomically accumulates on top

    s_depth[i] = depth;
    __syncthreads();

    // stable rank sort via broadcast float4 LDS reads
    const float4* sd4 = (const float4*)s_depth;
    int rank = 0;
    #pragma unroll 4
    for (int j4 = 0; j4 < P/4; ++j4) {
        const float4 d = sd4[j4];
        const int j = j4 * 4;
        rank += (d.x < depth) || (d.x == depth && j+0 < i);
        rank += (d.y < depth) || (d.y == depth && j+1 < i);
        rank += (d.z < depth) || (d.z == depth && j+2 < i);
        rank += (d.w < depth) || (d.w == depth && j+3 < i);
    }

    float* gp = ws + GPACK_OFF + rank * 12;
    gp[0]  = py;  gp[1]  = rowrad2; gp[2]  = px;  gp[3]  = ca;
    gp[4]  = cb;  gp[5]  = cc;      gp[6]  = op;  gp[7]  = depth;
    gp[8]  = cols[i*3+0]; gp[9] = cols[i*3+1]; gp[10] = cols[i*3+2]; gp[11] = 0.0f;
    ((int*)ws)[IDX_OFF + rank] = i;
    ((float2*)(ws + HDR_OFF))[rank] = make_float2(py, rowrad2);
}

template <int SEGS>
__global__ __launch_bounds__(256) void blend_kernel(
    float* __restrict__ ws, float* __restrict__ out)
{
    constexpr int PSEG = P / SEGS;          // 128
    __shared__ int   slist[PSEG];
    __shared__ int   sidx[PSEG];
    __shared__ int   snt[PSEG];
    __shared__ float sg[PSEG * 12];
    __shared__ int   swcnt[2];
    __shared__ int   s_n;

    const int row = blockIdx.x, seg = blockIdx.y;
    const int tid = threadIdx.x;
    const float fy = (float)row;

    // ---- prepass: row-cull 128 candidates, stable-compact survivor ranks ----
    bool hit = false;
    if (tid < PSEG) {
        const float2 h = ((const float2*)(ws + HDR_OFF))[seg * PSEG + tid];
        const float dyv = h.x - fy;
        hit = (dyv * dyv <= h.y);
    }
    const unsigned long long m = __ballot(hit);
    if (tid == 0)  swcnt[0] = __popcll(m);
    if (tid == 64) swcnt[1] = __popcll(m);
    __syncthreads();
    if (hit) {
        const int base = (tid >= 64) ? swcnt[0] : 0;
        const int pos  = base + __popcll(m & ((1ull << (tid & 63)) - 1ull));
        slist[pos] = seg * PSEG + tid;
    }
    if (tid == 0) s_n = swcnt[0] + swcnt[1];
    __syncthreads();
    const int n = s_n;

    // ---- stage survivors (48 B each) into LDS ----
    const float4* gp4 = (const float4*)(ws + GPACK_OFF);
    float4* sg4 = (float4*)sg;
    for (int t = tid; t < n * 3; t += 256) {
        const int j = t / 3, k = t - j * 3;
        sg4[t] = gp4[slist[j] * 3 + k];
    }
    const int* idx = ((const int*)ws) + IDX_OFF;
    for (int t = tid; t < n; t += 256) { sidx[t] = idx[slist[t]]; snt[t] = 0; }
    __syncthreads();

    // ---- blend over survivors only ----
    const float fx = (float)tid;
    const bool lead = ((tid & 63) == 0);
    float T = 1.0f, ar = 0.f, ag = 0.f, ab = 0.f, ad = 0.f;

    for (int j = 0; j < n; ++j) {
        const float4 h  = sg4[j*3+0];       // py, rowrad2, px, ca
        const float4 mm = sg4[j*3+1];       // cb, cc, op, dep
        const float4 cl = sg4[j*3+2];       // r, g, b, pad
        const float dx = h.z - fx;
        const float dy = h.x - fy;
        const float power = -0.5f*(h.w*dx*dx + mm.y*dy*dy) - mm.x*dx*dy;
        const float alpha = fminf(0.99f, mm.z * __expf(power));
        const bool keep = (power <= 0.0f) && (alpha >= (1.0f/255.0f));

        const unsigned long long km = __ballot(keep);
        if (lead && km) atomicAdd(&snt[j], __popcll(km));

        if (keep) {
            const float w = alpha * T;
            ar += w * cl.x; ag += w * cl.y; ab += w * cl.z; ad += w * mm.w;
            T *= (1.0f - alpha);
        }
    }
    __syncthreads();

    for (int t = tid; t < n; t += 256)
        if (snt[t]) atomicAdd(&out[NT_OFF + sidx[t]], (float)snt[t]);

    const int pix = row * W + tid;
    float* part = ws + PART_OFF;
    part[(0*SEGS + seg)*65536 + pix] = ar;
    part[(1*SEGS + seg)*65536 + pix] = ag;
    part[(2*SEGS + seg)*65536 + pix] = ab;
    part[(3*SEGS + seg)*65536 + pix] = ad;
    part[(4*SEGS + seg)*65536 + pix] = T;
}

template <int SEGS>
__global__ __launch_bounds__(256) void combine_kernel(
    const float* __restrict__ ws, const float* __restrict__ bg,
    float* __restrict__ out)
{
    const int pix = blockIdx.x * 256 + threadIdx.x;
    const float* part = ws + PART_OFF;
    float T = 1.0f, r = 0.f, g = 0.f, b = 0.f, d = 0.f;
    #pragma unroll
    for (int s = 0; s < SEGS; ++s) {
        const float pr = part[(0*SEGS + s)*65536 + pix];
        const float pg = part[(1*SEGS + s)*65536 + pix];
        const float pb = part[(2*SEGS + s)*65536 + pix];
        const float pd = part[(3*SEGS + s)*65536 + pix];
        const float pT = part[(4*SEGS + s)*65536 + pix];
        r += T * pr; g += T * pg; b += T * pb; d += T * pd;
        T *= pT;
    }
    out[COLOR_OFF + 0*65536 + pix] = r + T * bg[0];
    out[COLOR_OFF + 1*65536 + pix] = g + T * bg[1];
    out[COLOR_OFF + 2*65536 + pix] = b + T * bg[2];
    out[DEPTH_OFF + pix]           = d;
    out[OPAC_OFF  + pix]           = 1.0f - T;
}

// Fallback (ws too small for partials): one block per row, full 512 list.
__global__ __launch_bounds__(256) void blend_direct_kernel(
    float* __restrict__ ws, const float* __restrict__ bg, float* __restrict__ out)
{
    __shared__ int snt[P];
    for (int t = threadIdx.x; t < P; t += 256) snt[t] = 0;
    __syncthreads();

    const int row = blockIdx.x;
    const float fx = (float)threadIdx.x;
    const float fy = (float)row;
    const float4* gp4 = (const float4*)(ws + GPACK_OFF);
    const float2* hdr = (const float2*)(ws + HDR_OFF);
    const bool lead = ((threadIdx.x & 63) == 0);

    float T = 1.0f, ar = 0.f, ag = 0.f, ab = 0.f, ad = 0.f;
    for (int i = 0; i < P; ++i) {
        const float2 hh = hdr[i];
        const float dy = hh.x - fy;
        if (dy*dy > hh.y) continue;
        const float4 h  = gp4[i*3+0];
        const float4 mm = gp4[i*3+1];
        const float4 cl = gp4[i*3+2];
        const float dx = h.z - fx;
        const float power = -0.5f*(h.w*dx*dx + mm.y*dy*dy) - mm.x*dx*dy;
        const float alpha = fminf(0.99f, mm.z * __expf(power));
        const bool keep = (power <= 0.0f) && (alpha >= (1.0f/255.0f));
        const unsigned long long km = __ballot(keep);
        if (lead && km) atomicAdd(&snt[i], __popcll(km));
        if (keep) {
            const float w = alpha * T;
            ar += w * cl.x; ag += w * cl.y; ab += w * cl.z; ad += w * mm.w;
            T *= (1.0f - alpha);
        }
    }
    __syncthreads();
    const int* idx = ((const int*)ws) + IDX_OFF;
    for (int t = threadIdx.x; t < P; t += 256)
        if (snt[t]) atomicAdd(&out[NT_OFF + idx[t]], (float)snt[t]);

    const int pix = row * W + threadIdx.x;
    out[COLOR_OFF + 0*65536 + pix] = ar + T * bg[0];
    out[COLOR_OFF + 1*65536 + pix] = ag + T * bg[1];
    out[COLOR_OFF + 2*65536 + pix] = ab + T * bg[2];
    out[DEPTH_OFF + pix]           = ad;
    out[OPAC_OFF  + pix]           = 1.0f - T;
}

extern "C" void kernel_launch(void* const* d_in, const int* in_sizes, int n_in,
                              void* d_out, int out_size, void* d_ws, size_t ws_size,
                              hipStream_t stream) {
    const float* means3D = (const float*)d_in[0];
    const float* scales  = (const float*)d_in[1];
    const float* rots    = (const float*)d_in[2];
    const float* opacs   = (const float*)d_in[3];
    const float* cols    = (const float*)d_in[4];
    const float* vm      = (const float*)d_in[5];
    const float* pm      = (const float*)d_in[6];
    const float* bg      = (const float*)d_in[8];
    float* out = (float*)d_out;
    float* ws  = (float*)d_ws;

    prep_sort_kernel<<<1, 512, 0, stream>>>(means3D, scales, rots, opacs, cols,
                                            vm, pm, out, ws);

    const size_t need = (size_t)(PART_OFF + 5 * S * 65536) * 4;
    if (ws_size >= need) {
        blend_kernel<S><<<dim3(H, S), 256, 0, stream>>>(ws, out);
        combine_kernel<S><<<(H * W) / 256, 256, 0, stream>>>(ws, bg, out);
    } else {
        blend_direct_kernel<<<H, 256, 0, stream>>>(ws, bg, out);
    }
}